// Round 1
// baseline (791.700 us; speedup 1.0000x reference)
//
#include <hip/hip_runtime.h>
#include <stdint.h>

#define NROWS   1024
#define NV      100000
#define NSEL    101            // K+1
#define NEED    101            // threshold slack: 100 + possibly-unmasked target
#define POOLW   480            // per-wave pool entries
#define NWAVE   8
#define NTHR    512
#define STRIPE  12500          // NV / NWAVE
#define FULLIT  48             // 48*256 = 12288; tail = 212 = 53 lanes * 4

__device__ __forceinline__ uint32_t rotl32(uint32_t x, uint32_t r) {
  return (x << r) | (x >> (32u - r));   // pattern-matched to v_alignbit_b32
}

// JAX threefry2x32, partitionable path, 4 consecutive counters interleaved:
// bits(n) = o0 ^ o1 of threefry2x32(key=(0,42), counts=(hi=0, lo=n)).
// Bit-exact vs reference (absmax 0.0 established for the scalar version;
// this is the same integer op sequence per element, just batched x4 for ILP).
__device__ __forceinline__ void jax_bits4(uint32_t nb, uint32_t bits[4]) {
  const uint32_t K1 = 42u;
  const uint32_t K2 = 0x1BD11BF0u;
  uint32_t x0[4], x1[4];
  #pragma unroll
  for (int i = 0; i < 4; ++i) { x0[i] = 0u; x1[i] = nb + K1 + (uint32_t)i; }
#define TF4(r) { _Pragma("unroll") for (int i = 0; i < 4; ++i) { \
    x0[i] += x1[i]; x1[i] = rotl32(x1[i], (r)); x1[i] ^= x0[i]; } }
#define INJ4(ka, kb) { _Pragma("unroll") for (int i = 0; i < 4; ++i) { \
    x0[i] += (ka); x1[i] += (kb); } }
  TF4(13u) TF4(15u) TF4(26u) TF4(6u)
  INJ4(K1, K2 + 1u)
  TF4(17u) TF4(29u) TF4(16u) TF4(24u)
  INJ4(K2, 2u)
  TF4(13u) TF4(15u) TF4(26u) TF4(6u)
  INJ4(0u, K1 + 3u)
  TF4(17u) TF4(29u) TF4(16u) TF4(24u)
  INJ4(K1, K2 + 4u)
  TF4(13u) TF4(15u) TF4(26u) TF4(6u)
  INJ4(K2, 5u)
#undef TF4
#undef INJ4
  #pragma unroll
  for (int i = 0; i < 4; ++i) bits[i] = x0[i] ^ x1[i];
}

__device__ __forceinline__ float blk_reduce(float x, int tid, float* wred, bool is_max) {
  #pragma unroll
  for (int off = 32; off >= 1; off >>= 1) {
    float o = __shfl_down(x, off);
    x = is_max ? fmaxf(x, o) : (x + o);
  }
  if ((tid & 63) == 0) wred[tid >> 6] = x;
  __syncthreads();
  float r = wred[0];
  #pragma unroll
  for (int w = 1; w < NTHR / 64; ++w)
    r = is_max ? fmaxf(r, wred[w]) : (r + wred[w]);
  __syncthreads();
  return r;
}

// bin b lives at phys ((b&31)<<6)|(b>>5): scan reads are stride-64 (2-way, free)
__device__ __forceinline__ uint32_t hist_phys(uint32_t b) {
  return ((b & 31u) << 6) | (b >> 5);
}

// smallest real float f with sortable_key(f) >= (b<<21); pred (val>=f) <=> bin(val)>=b
__device__ __forceinline__ float binlow_float(uint32_t b) {
  uint32_t k = b << 21;
  if (k & 0x80000000u) {
    uint32_t fb = k ^ 0x80000000u;
    return (fb >= 0x7F800000u) ? INFINITY : __uint_as_float(fb);
  } else {
    uint32_t fb = ~k;
    return (fb >= 0xFF800000u) ? -INFINITY : __uint_as_float(fb);
  }
}

// wave-local scan of shared hist: highest bin b with suffix-count >= need, else -1.
// Racy reads are safe: counts only grow, so any read <= true count.
__device__ __forceinline__ int wave_scan_thr(volatile uint32_t* hist, int lane, uint32_t need) {
  uint32_t sum = 0;
  #pragma unroll
  for (int j = 0; j < 32; ++j) sum += hist[(j << 6) | lane];
  uint32_t suf = sum;
  #pragma unroll
  for (int off = 1; off < 64; off <<= 1) {
    uint32_t o = __shfl_down(suf, off);
    if (lane + off < 64) suf += o;
  }
  const uint32_t sufnext = suf - sum;
  int b = -1;
  if (suf >= need && sufnext < need) {
    uint32_t cum = sufnext;
    int j = 31;
    for (;; --j) {
      cum += hist[(j << 6) | lane];
      if (cum >= need || j == 0) break;
    }
    b = lane * 32 + j;
  }
  #pragma unroll
  for (int off = 32; off >= 1; off >>= 1) b = max(b, __shfl_xor(b, off));
  return b;
}

// monotone raise of shared threshold; out-of-order thrf writes are stale-LOW -> safe
__device__ __forceinline__ void raise_thr(int b, int lane, uint32_t* thrkey, volatile float* thrf) {
  if (b < 0) return;
  if (lane == 0) {
    uint32_t old = atomicMax(thrkey, (uint32_t)b);
    if ((uint32_t)b > old) *thrf = binlow_float((uint32_t)b);
  }
}

// 4 elements: batched threefry (4 interleaved chains), combined prefilter ballot;
// full gumbel only for elements where some lane might pass. Element order, pool
// insertion order, and all store-side semantics identical to the scalar version.
// Bound: g = -ln(-ln u) <= -ln(1-u) <= (clz(2^23 - u23) - 8)*ln2  (since -ln u >= 1-u).
__device__ __forceinline__ void proc4(
    float4 a, uint32_t nb, uint32_t e0, float thrf, float thr_s, int lane,
    float* pv_w, uint32_t* pi_w, uint32_t* hist, uint32_t& cnt) {
  uint32_t bits[4];
  jax_bits4(nb, bits);
  const float lg[4] = {a.x, a.y, a.z, a.w};
  bool maybe[4];
  #pragma unroll
  for (int i = 0; i < 4; ++i) {
    const uint32_t m = 0x800000u - (bits[i] >> 9);        // in [1, 2^23]
    const float clzf = (float)__clz((int)(m | 1u));       // m>=1: |1 keeps clz, kills zero-guard
    // skip if clz < (thrf - logit)/ln2 + 8;  thr_s = thrf/ln2 + 8 (wave-uniform)
    const float req = fmaf(lg[i], -1.4426950408889634f, thr_s);
    maybe[i] = (clzf >= req);                             // NaN logit => false
  }
  if (__ballot(maybe[0] | maybe[1] | maybe[2] | maybe[3]) == 0ull) return;
  #pragma unroll
  for (int i = 0; i < 4; ++i) {
    if (__ballot(maybe[i]) == 0ull) continue;
    const uint32_t b23 = bits[i] >> 9;
    float f1 = __uint_as_float(b23 | 0x3f800000u) - 1.0f;
    float u = fmaxf(f1, 1.1754943508222875e-38f);
    const float g = -__logf(-__logf(u));                  // exact reference gumbel
    const float val = lg[i] + g;
    const bool pred = maybe[i] && (val >= thrf);
    const unsigned long long mk = __ballot(pred);
    if (mk == 0ull) continue;
    const uint32_t pos = cnt + (uint32_t)__popcll(mk & ((1ull << lane) - 1ull));
    if (pred && pos < (uint32_t)POOLW) {
      pv_w[pos] = val;
      pi_w[pos] = e0 + (uint32_t)i;
      uint32_t fb = __float_as_uint(val);
      uint32_t key = fb ^ (uint32_t)(((int32_t)fb >> 31) | (int32_t)0x80000000);
      atomicAdd(&hist[hist_phys(key >> 21)], 1u);         // hist counts stored elems only
    }
    cnt += (uint32_t)__popcll(mk);
  }
}

__global__ void __launch_bounds__(NTHR, 8)
nce_row_kernel(const float* __restrict__ noise, const float* __restrict__ actual,
               const int* __restrict__ target, float* __restrict__ acc,
               uint32_t* __restrict__ ticket, float* __restrict__ out) {
  const int row = blockIdx.x;
  const int tid = threadIdx.x;
  const int lane = tid & 63;
  const uint32_t w = (uint32_t)tid >> 6;

  __shared__ float    pv[NWAVE * POOLW];
  __shared__ uint32_t pi_[NWAVE * POOLW];
  __shared__ uint32_t uni[2048];        // hist during stream; mv/mi at merge
  __shared__ uint32_t s_cnt[NWAVE];
  __shared__ uint32_t s_thrkey;
  __shared__ float    s_thrf;
  __shared__ float    s_thrf_final;
  __shared__ uint32_t s_mcnt;
  __shared__ float    s_wred[NTHR / 64];

  uint32_t* hist = uni;
  float*    mv   = (float*)uni;         // [0..1023]   (reused after final scan)
  uint32_t* mi   = uni + 1024;          // [0..1023]

  for (int i = tid; i < 2048; i += NTHR) hist[i] = 0u;
  if (tid == 0) { s_thrkey = 0u; s_thrf = -INFINITY; s_mcnt = 0u; }
  __syncthreads();

  const float* rowp = noise + (size_t)row * NV;
  const uint32_t tgt = (uint32_t)target[row];
  const uint32_t nbase = (uint32_t)row * (uint32_t)NV;
  const uint32_t stripe0 = w * (uint32_t)STRIPE;
  const float* sp = rowp + stripe0;
  float*    pv_w = pv  + w * POOLW;
  uint32_t* pi_w = pi_ + w * POOLW;
  volatile float* vthrf = &s_thrf;

  uint32_t cnt = 0;
  const float qnan = __int_as_float(0x7fc00000);

  // tile loader: tiles 0..47 full (256 elems), tile 48 = tail (53 lanes x 4).
  // Invalid tail lanes get qnan logits (fail prefilter; never stored).
  auto ldtile = [&](int t) -> float4 {
    if (t < FULLIT) return *reinterpret_cast<const float4*>(sp + t * 256 + lane * 4);
    if (lane < 53)  return *reinterpret_cast<const float4*>(sp + FULLIT * 256 + lane * 4);
    return make_float4(qnan, qnan, qnan, qnan);
  };

  // 2-deep prefetch: load of tile it+2 issued while tile it is processed,
  // so the vmcnt wait has ~2 iterations of VALU work of slack (> HBM latency).
  float4 a0 = ldtile(0);
  float4 a1 = ldtile(1);

  for (int it = 0; it < FULLIT; ++it) {
    float4 a2 = (it + 2 <= FULLIT) ? ldtile(it + 2)
                                   : make_float4(0.0f, 0.0f, 0.0f, 0.0f);

    const float thrf = *vthrf;                        // monotone, stale-low safe
    const float thr_s = fmaf(thrf, 1.4426950408889634f, 8.0f);
    const uint32_t e0 = stripe0 + (uint32_t)(it * 256 + lane * 4);
    proc4(a0, nbase + e0, e0, thrf, thr_s, lane, pv_w, pi_w, hist, cnt);

    if (cnt > (uint32_t)(POOLW - 256)) {
      // compact: raise thr from hist, then refilter own pool in place
      int b = wave_scan_thr(hist, lane, NEED);
      raise_thr(b, lane, &s_thrkey, vthrf);
      const float tf = *vthrf;
      const uint32_t n0 = min(cnt, (uint32_t)POOLW);
      uint32_t nc = 0;
      for (uint32_t p0 = 0; p0 < n0; p0 += 64) {
        const uint32_t p = p0 + (uint32_t)lane;
        const bool v = (p < n0);
        float vv = 0.0f; uint32_t ii = 0;
        if (v) { vv = pv_w[p]; ii = pi_w[p]; }
        const bool keep = v && (vv >= tf);
        const unsigned long long km = __ballot(keep);
        const uint32_t np = nc + (uint32_t)__popcll(km & ((1ull << lane) - 1ull));
        if (keep) { pv_w[np] = vv; pi_w[np] = ii; }
        nc += (uint32_t)__popcll(km);
      }
      cnt = nc;
    } else if ((it & 15) == 7) {
      int b = wave_scan_thr(hist, lane, NEED);
      raise_thr(b, lane, &s_thrkey, vthrf);
    }

    a0 = a1; a1 = a2;
  }

  { // tail tile (already resident in a0; invalid lanes hold qnan)
    const float thrf = *vthrf;
    const float thr_s = fmaf(thrf, 1.4426950408889634f, 8.0f);
    const uint32_t e0 = stripe0 + (uint32_t)(FULLIT * 256 + lane * 4);
    proc4(a0, nbase + e0, e0, thrf, thr_s, lane, pv_w, pi_w, hist, cnt);
  }

  if (lane == 0) s_cnt[w] = min(cnt, (uint32_t)POOLW);
  __syncthreads();

  // exact final threshold from complete hist (wave 0)
  if (tid < 64) {
    int b = wave_scan_thr(hist, lane, NEED);          // b >= 0 guaranteed (hist >= NEED)
    if (lane == 0) s_thrf_final = binlow_float((uint32_t)(b < 0 ? 0 : b));
  }
  __syncthreads();
  const float tf = s_thrf_final;

  // merge-compact all pools' entries >= tf (excluding target) into mv/mi (aliases hist)
  for (uint32_t s = tid; s < (uint32_t)(NWAVE * POOLW); s += NTHR) {
    const uint32_t wq = s / POOLW;
    const uint32_t p = s - wq * POOLW;
    bool keep = (p < s_cnt[wq]);
    float vv = 0.0f; uint32_t ii = 0;
    if (keep) {
      vv = pv[s]; ii = pi_[s];
      keep = (vv >= tf) && (ii != tgt);
    }
    const unsigned long long km = __ballot(keep);
    const uint32_t nb2 = (uint32_t)__popcll(km);
    if (nb2) {
      uint32_t base = 0;
      if (lane == 0) base = atomicAdd(&s_mcnt, nb2);
      base = __shfl(base, 0);
      if (keep) {
        const uint32_t pos = base + (uint32_t)__popcll(km & ((1ull << lane) - 1ull));
        if (pos < 1024u) { mv[pos] = vv; mi[pos] = ii; }
      }
    }
  }
  __syncthreads();
  const uint32_t mc = min(s_mcnt, 1024u);
  for (uint32_t i = mc + tid; i < 1024u; i += NTHR) { mv[i] = -INFINITY; mi[i] = 0xFFFFFFFFu; }
  __syncthreads();

  // bitonic sort 1024 desc by (val, idx asc) — matches lax.top_k tie-breaking
  for (uint32_t ksz = 2; ksz <= 1024u; ksz <<= 1) {
    for (uint32_t jsz = ksz >> 1; jsz >= 1; jsz >>= 1) {
      for (uint32_t i = tid; i < 1024u; i += NTHR) {
        const uint32_t ixj = i ^ jsz;
        if (ixj > i) {
          const bool desc = ((i & ksz) == 0);
          float va = mv[i], vb = mv[ixj];
          uint32_t ia = mi[i], ib = mi[ixj];
          const bool a_less = (va < vb) || (va == vb && ia > ib);
          if (desc ? a_less : !a_less) {
            mv[i] = vb; mv[ixj] = va; mi[i] = ib; mi[ixj] = ia;
          }
        }
      }
      __syncthreads();
    }
  }

  // scoring: softmax over gathered noise logits & actual logits
  float nl = -INFINITY, al = -INFINITY;
  if (tid < NSEL) {
    const uint32_t idx = (tid == 0) ? tgt : mi[tid - 1];
    nl = rowp[idx];                            // original (unmasked) logits
    al = actual[(size_t)row * NSEL + tid];
  }
  const float mn = blk_reduce(nl, tid, s_wred, true);
  const float ma = blk_reduce(al, tid, s_wred, true);
  const float en = (tid < NSEL) ? __expf(nl - mn) : 0.0f;
  const float ea = (tid < NSEL) ? __expf(al - ma) : 0.0f;
  const float sn = blk_reduce(en, tid, s_wred, false);
  const float sa = blk_reduce(ea, tid, s_wred, false);

  float contrib = 0.0f;
  if (tid < NSEL) {
    const float npj = en / sn;
    const float apj = ea / sa;
    const float deno = 100.0f * npj + apj + 1e-6f;
    float t = (tid == 0) ? (apj / deno) : (npj / deno);
    if (t == 1.0f) t = 1.0f + 1e-6f;           // exact reference quirk
    contrib = logf(t);
  }
  const float tot = blk_reduce(contrib, tid, s_wred, false);

  if (tid == 0) {
    atomicAdd(acc, tot);
    __threadfence();
    const uint32_t tk = atomicAdd(ticket, 1u);
    if (tk == (uint32_t)(NROWS - 1)) {
      const float total = atomicAdd(acc, 0.0f);
      out[0] = -total / (1024.0f * 101.0f);
    }
  }
}

extern "C" void kernel_launch(void* const* d_in, const int* in_sizes, int n_in,
                              void* d_out, int out_size, void* d_ws, size_t ws_size,
                              hipStream_t stream) {
  const float* noise  = (const float*)d_in[0];
  const float* actual = (const float*)d_in[1];
  const int*   target = (const int*)d_in[2];
  float* out = (float*)d_out;
  float*    acc    = (float*)d_ws;
  uint32_t* ticket = (uint32_t*)d_ws + 1;

  hipMemsetAsync(d_ws, 0, 8, stream);
  nce_row_kernel<<<NROWS, NTHR, 0, stream>>>(noise, actual, target, acc, ticket, out);
}

// Round 2
// 780.930 us; speedup vs baseline: 1.0138x; 1.0138x over previous
//
#include <hip/hip_runtime.h>
#include <stdint.h>

#define NROWS   1024
#define NV      100000
#define NSEL    101            // K+1
#define NEED    101            // threshold slack: 100 + possibly-unmasked target
#define POOLW   480            // per-wave pool entries
#define NWAVE   8
#define NTHR    512
#define STRIPE  12500          // NV / NWAVE
#define FULLIT  48             // 48*256 = 12288; tail = 212 = 53 lanes * 4

__device__ __forceinline__ uint32_t rotl32(uint32_t x, uint32_t r) {
  return (x << r) | (x >> (32u - r));   // pattern-matched to v_alignbit_b32
}

// JAX threefry2x32, partitionable path, TWO consecutive counters interleaved:
// bits(n) = o0 ^ o1 of threefry2x32(key=(0,42), counts=(hi=0, lo=n)).
// Same integer op sequence per element as the verified scalar version (absmax
// 0.0); x2 batching only interleaves two independent chains for ILP.
// Live state: 4 regs (x0a,x1a,x0b,x1b) — cheap under the 64-VGPR budget.
__device__ __forceinline__ void jax_bits2(uint32_t nb, uint32_t bits[2]) {
  const uint32_t K1 = 42u;
  const uint32_t K2 = 0x1BD11BF0u;
  uint32_t x0a = 0u, x1a = nb + K1;
  uint32_t x0b = 0u, x1b = nb + K1 + 1u;
#define TF2(r) { x0a += x1a; x1a = rotl32(x1a, (r)); x1a ^= x0a; \
                 x0b += x1b; x1b = rotl32(x1b, (r)); x1b ^= x0b; }
#define INJ2(ka, kb) { x0a += (ka); x1a += (kb); x0b += (ka); x1b += (kb); }
  TF2(13u) TF2(15u) TF2(26u) TF2(6u)
  INJ2(K1, K2 + 1u)
  TF2(17u) TF2(29u) TF2(16u) TF2(24u)
  INJ2(K2, 2u)
  TF2(13u) TF2(15u) TF2(26u) TF2(6u)
  INJ2(0u, K1 + 3u)
  TF2(17u) TF2(29u) TF2(16u) TF2(24u)
  INJ2(K1, K2 + 4u)
  TF2(13u) TF2(15u) TF2(26u) TF2(6u)
  INJ2(K2, 5u)
#undef TF2
#undef INJ2
  bits[0] = x0a ^ x1a;
  bits[1] = x0b ^ x1b;
}

__device__ __forceinline__ float blk_reduce(float x, int tid, float* wred, bool is_max) {
  #pragma unroll
  for (int off = 32; off >= 1; off >>= 1) {
    float o = __shfl_down(x, off);
    x = is_max ? fmaxf(x, o) : (x + o);
  }
  if ((tid & 63) == 0) wred[tid >> 6] = x;
  __syncthreads();
  float r = wred[0];
  #pragma unroll
  for (int w = 1; w < NTHR / 64; ++w)
    r = is_max ? fmaxf(r, wred[w]) : (r + wred[w]);
  __syncthreads();
  return r;
}

// bin b lives at phys ((b&31)<<6)|(b>>5): scan reads are stride-64 (2-way, free)
__device__ __forceinline__ uint32_t hist_phys(uint32_t b) {
  return ((b & 31u) << 6) | (b >> 5);
}

// smallest real float f with sortable_key(f) >= (b<<21); pred (val>=f) <=> bin(val)>=b
__device__ __forceinline__ float binlow_float(uint32_t b) {
  uint32_t k = b << 21;
  if (k & 0x80000000u) {
    uint32_t fb = k ^ 0x80000000u;
    return (fb >= 0x7F800000u) ? INFINITY : __uint_as_float(fb);
  } else {
    uint32_t fb = ~k;
    return (fb >= 0xFF800000u) ? -INFINITY : __uint_as_float(fb);
  }
}

// wave-local scan of shared hist: highest bin b with suffix-count >= need, else -1.
// Racy reads are safe: counts only grow, so any read <= true count.
__device__ __forceinline__ int wave_scan_thr(volatile uint32_t* hist, int lane, uint32_t need) {
  uint32_t sum = 0;
  #pragma unroll
  for (int j = 0; j < 32; ++j) sum += hist[(j << 6) | lane];
  uint32_t suf = sum;
  #pragma unroll
  for (int off = 1; off < 64; off <<= 1) {
    uint32_t o = __shfl_down(suf, off);
    if (lane + off < 64) suf += o;
  }
  const uint32_t sufnext = suf - sum;
  int b = -1;
  if (suf >= need && sufnext < need) {
    uint32_t cum = sufnext;
    int j = 31;
    for (;; --j) {
      cum += hist[(j << 6) | lane];
      if (cum >= need || j == 0) break;
    }
    b = lane * 32 + j;
  }
  #pragma unroll
  for (int off = 32; off >= 1; off >>= 1) b = max(b, __shfl_xor(b, off));
  return b;
}

// monotone raise of shared threshold; out-of-order thrf writes are stale-LOW -> safe
__device__ __forceinline__ void raise_thr(int b, int lane, uint32_t* thrkey, volatile float* thrf) {
  if (b < 0) return;
  if (lane == 0) {
    uint32_t old = atomicMax(thrkey, (uint32_t)b);
    if ((uint32_t)b > old) *thrf = binlow_float((uint32_t)b);
  }
}

// Two elements: x2-interleaved threefry, one combined skip-ballot, then the
// exact per-element path of the verified scalar version (same order, same
// pool/hist/cnt updates). Bound: g = -ln(-ln u) <= -ln(1-u) <=
// (clz(2^23 - u23) - 8)*ln2  (since -ln u >= 1-u).
__device__ __forceinline__ void proc_pair(
    float la, float lb, uint32_t n0, uint32_t e0, float thrf, float thr_s, int lane,
    float* pv_w, uint32_t* pi_w, uint32_t* hist, uint32_t& cnt) {
  uint32_t bits[2];
  jax_bits2(n0, bits);
  const uint32_t m0 = 0x800000u - (bits[0] >> 9);       // in [1, 2^23]
  const uint32_t m1 = 0x800000u - (bits[1] >> 9);
  const float c0 = (float)__clz((int)(m0 | 1u));        // m>=1: |1 keeps clz, kills zero-guard
  const float c1 = (float)__clz((int)(m1 | 1u));
  // skip if clz < (thrf - logit)/ln2 + 8;  thr_s = thrf/ln2 + 8 (wave-uniform)
  const float q0 = fmaf(la, -1.4426950408889634f, thr_s);
  const float q1 = fmaf(lb, -1.4426950408889634f, thr_s);
  const bool mA = (c0 >= q0);                           // NaN logit => false
  const bool mB = (c1 >= q1);
  if (__ballot(mA || mB) == 0ull) return;
  #pragma unroll
  for (int i = 0; i < 2; ++i) {
    const bool mi_ = i ? mB : mA;
    const float lg = i ? lb : la;
    if (__ballot(mi_) == 0ull) continue;
    const uint32_t b23 = bits[i] >> 9;
    float f1 = __uint_as_float(b23 | 0x3f800000u) - 1.0f;
    float u = fmaxf(f1, 1.1754943508222875e-38f);
    const float g = -__logf(-__logf(u));                // exact reference gumbel
    const float val = lg + g;
    const bool pred = mi_ && (val >= thrf);
    const unsigned long long mk = __ballot(pred);
    if (mk == 0ull) continue;
    const uint32_t pos = cnt + (uint32_t)__popcll(mk & ((1ull << lane) - 1ull));
    if (pred && pos < (uint32_t)POOLW) {
      pv_w[pos] = val;
      pi_w[pos] = e0 + (uint32_t)i;
      uint32_t fb = __float_as_uint(val);
      uint32_t key = fb ^ (uint32_t)(((int32_t)fb >> 31) | (int32_t)0x80000000);
      atomicAdd(&hist[hist_phys(key >> 21)], 1u);       // hist counts stored elems only
    }
    cnt += (uint32_t)__popcll(mk);
  }
}

// Explicit waves/EU: 8 waves/SIMD -> VGPR cap 64 (512-reg file / 8), which is
// exactly what the LDS-limited 4-blocks/CU residency needs. __launch_bounds__'
// 2nd arg proved to lower to a 32-VGPR cap (R0/R1 both pinned at 32; R1's
// extra live state spilled: FETCH +36MB / WRITE +22MB). This attribute is
// unambiguous at the LLVM level.
__global__ void __launch_bounds__(NTHR)
__attribute__((amdgpu_waves_per_eu(8)))
nce_row_kernel(const float* __restrict__ noise, const float* __restrict__ actual,
               const int* __restrict__ target, float* __restrict__ acc,
               uint32_t* __restrict__ ticket, float* __restrict__ out) {
  const int row = blockIdx.x;
  const int tid = threadIdx.x;
  const int lane = tid & 63;
  const uint32_t w = (uint32_t)tid >> 6;

  __shared__ float    pv[NWAVE * POOLW];
  __shared__ uint32_t pi_[NWAVE * POOLW];
  __shared__ uint32_t uni[2048];        // hist during stream; mv/mi at merge
  __shared__ uint32_t s_cnt[NWAVE];
  __shared__ uint32_t s_thrkey;
  __shared__ float    s_thrf;
  __shared__ float    s_thrf_final;
  __shared__ uint32_t s_mcnt;
  __shared__ float    s_wred[NTHR / 64];

  uint32_t* hist = uni;
  float*    mv   = (float*)uni;         // [0..1023]   (reused after final scan)
  uint32_t* mi   = uni + 1024;          // [0..1023]

  for (int i = tid; i < 2048; i += NTHR) hist[i] = 0u;
  if (tid == 0) { s_thrkey = 0u; s_thrf = -INFINITY; s_mcnt = 0u; }
  __syncthreads();

  const float* rowp = noise + (size_t)row * NV;
  const uint32_t tgt = (uint32_t)target[row];
  const uint32_t nbase = (uint32_t)row * (uint32_t)NV;
  const uint32_t stripe0 = w * (uint32_t)STRIPE;
  const float* sp = rowp + stripe0;
  float*    pv_w = pv  + w * POOLW;
  uint32_t* pi_w = pi_ + w * POOLW;
  volatile float* vthrf = &s_thrf;

  uint32_t cnt = 0;
  const float qnan = __int_as_float(0x7fc00000);

  float4 a = *reinterpret_cast<const float4*>(sp + lane * 4);

  for (int it = 0; it < FULLIT; ++it) {
    float4 an;
    if (it < FULLIT - 1) {
      an = *reinterpret_cast<const float4*>(sp + (it + 1) * 256 + lane * 4);
    } else if (lane < 53) {
      an = *reinterpret_cast<const float4*>(sp + FULLIT * 256 + lane * 4);
    }

    const float thrf = *vthrf;                        // monotone, stale-low safe
    const float thr_s = fmaf(thrf, 1.4426950408889634f, 8.0f);
    const uint32_t e0 = stripe0 + (uint32_t)(it * 256 + lane * 4);
    proc_pair(a.x, a.y, nbase + e0,      e0,      thrf, thr_s, lane, pv_w, pi_w, hist, cnt);
    proc_pair(a.z, a.w, nbase + e0 + 2u, e0 + 2u, thrf, thr_s, lane, pv_w, pi_w, hist, cnt);

    if (cnt > (uint32_t)(POOLW - 256)) {
      // compact: raise thr from hist, then refilter own pool in place
      int b = wave_scan_thr(hist, lane, NEED);
      raise_thr(b, lane, &s_thrkey, vthrf);
      const float tf = *vthrf;
      const uint32_t n0 = min(cnt, (uint32_t)POOLW);
      uint32_t nc = 0;
      for (uint32_t p0 = 0; p0 < n0; p0 += 64) {
        const uint32_t p = p0 + (uint32_t)lane;
        const bool v = (p < n0);
        float vv = 0.0f; uint32_t ii = 0;
        if (v) { vv = pv_w[p]; ii = pi_w[p]; }
        const bool keep = v && (vv >= tf);
        const unsigned long long km = __ballot(keep);
        const uint32_t np = nc + (uint32_t)__popcll(km & ((1ull << lane) - 1ull));
        if (keep) { pv_w[np] = vv; pi_w[np] = ii; }
        nc += (uint32_t)__popcll(km);
      }
      cnt = nc;
    } else if ((it & 15) == 7) {
      int b = wave_scan_thr(hist, lane, NEED);
      raise_thr(b, lane, &s_thrkey, vthrf);
    }
    a = an;
  }

  { // tail: 212 elements = 53 lanes x 4; invalid lanes get NaN logits (fail prefilter)
    const float thrf = *vthrf;
    const float thr_s = fmaf(thrf, 1.4426950408889634f, 8.0f);
    const uint32_t e0 = stripe0 + (uint32_t)(FULLIT * 256 + lane * 4);
    const bool lv = (lane < 53);
    const float tx = lv ? a.x : qnan;
    const float ty = lv ? a.y : qnan;
    const float tz = lv ? a.z : qnan;
    const float tw = lv ? a.w : qnan;
    proc_pair(tx, ty, nbase + e0,      e0,      thrf, thr_s, lane, pv_w, pi_w, hist, cnt);
    proc_pair(tz, tw, nbase + e0 + 2u, e0 + 2u, thrf, thr_s, lane, pv_w, pi_w, hist, cnt);
  }

  if (lane == 0) s_cnt[w] = min(cnt, (uint32_t)POOLW);
  __syncthreads();

  // exact final threshold from complete hist (wave 0)
  if (tid < 64) {
    int b = wave_scan_thr(hist, lane, NEED);          // b >= 0 guaranteed (hist >= NEED)
    if (lane == 0) s_thrf_final = binlow_float((uint32_t)(b < 0 ? 0 : b));
  }
  __syncthreads();
  const float tf = s_thrf_final;

  // merge-compact all pools' entries >= tf (excluding target) into mv/mi (aliases hist)
  for (uint32_t s = tid; s < (uint32_t)(NWAVE * POOLW); s += NTHR) {
    const uint32_t wq = s / POOLW;
    const uint32_t p = s - wq * POOLW;
    bool keep = (p < s_cnt[wq]);
    float vv = 0.0f; uint32_t ii = 0;
    if (keep) {
      vv = pv[s]; ii = pi_[s];
      keep = (vv >= tf) && (ii != tgt);
    }
    const unsigned long long km = __ballot(keep);
    const uint32_t nb2 = (uint32_t)__popcll(km);
    if (nb2) {
      uint32_t base = 0;
      if (lane == 0) base = atomicAdd(&s_mcnt, nb2);
      base = __shfl(base, 0);
      if (keep) {
        const uint32_t pos = base + (uint32_t)__popcll(km & ((1ull << lane) - 1ull));
        if (pos < 1024u) { mv[pos] = vv; mi[pos] = ii; }
      }
    }
  }
  __syncthreads();
  const uint32_t mc = min(s_mcnt, 1024u);
  for (uint32_t i = mc + tid; i < 1024u; i += NTHR) { mv[i] = -INFINITY; mi[i] = 0xFFFFFFFFu; }
  __syncthreads();

  // bitonic sort 1024 desc by (val, idx asc) — matches lax.top_k tie-breaking
  for (uint32_t ksz = 2; ksz <= 1024u; ksz <<= 1) {
    for (uint32_t jsz = ksz >> 1; jsz >= 1; jsz >>= 1) {
      for (uint32_t i = tid; i < 1024u; i += NTHR) {
        const uint32_t ixj = i ^ jsz;
        if (ixj > i) {
          const bool desc = ((i & ksz) == 0);
          float va = mv[i], vb = mv[ixj];
          uint32_t ia = mi[i], ib = mi[ixj];
          const bool a_less = (va < vb) || (va == vb && ia > ib);
          if (desc ? a_less : !a_less) {
            mv[i] = vb; mv[ixj] = va; mi[i] = ib; mi[ixj] = ia;
          }
        }
      }
      __syncthreads();
    }
  }

  // scoring: softmax over gathered noise logits & actual logits
  float nl = -INFINITY, al = -INFINITY;
  if (tid < NSEL) {
    const uint32_t idx = (tid == 0) ? tgt : mi[tid - 1];
    nl = rowp[idx];                            // original (unmasked) logits
    al = actual[(size_t)row * NSEL + tid];
  }
  const float mn = blk_reduce(nl, tid, s_wred, true);
  const float ma = blk_reduce(al, tid, s_wred, true);
  const float en = (tid < NSEL) ? __expf(nl - mn) : 0.0f;
  const float ea = (tid < NSEL) ? __expf(al - ma) : 0.0f;
  const float sn = blk_reduce(en, tid, s_wred, false);
  const float sa = blk_reduce(ea, tid, s_wred, false);

  float contrib = 0.0f;
  if (tid < NSEL) {
    const float npj = en / sn;
    const float apj = ea / sa;
    const float deno = 100.0f * npj + apj + 1e-6f;
    float t = (tid == 0) ? (apj / deno) : (npj / deno);
    if (t == 1.0f) t = 1.0f + 1e-6f;           // exact reference quirk
    contrib = logf(t);
  }
  const float tot = blk_reduce(contrib, tid, s_wred, false);

  if (tid == 0) {
    atomicAdd(acc, tot);
    __threadfence();
    const uint32_t tk = atomicAdd(ticket, 1u);
    if (tk == (uint32_t)(NROWS - 1)) {
      const float total = atomicAdd(acc, 0.0f);
      out[0] = -total / (1024.0f * 101.0f);
    }
  }
}

extern "C" void kernel_launch(void* const* d_in, const int* in_sizes, int n_in,
                              void* d_out, int out_size, void* d_ws, size_t ws_size,
                              hipStream_t stream) {
  const float* noise  = (const float*)d_in[0];
  const float* actual = (const float*)d_in[1];
  const int*   target = (const int*)d_in[2];
  float* out = (float*)d_out;
  float*    acc    = (float*)d_ws;
  uint32_t* ticket = (uint32_t*)d_ws + 1;

  hipMemsetAsync(d_ws, 0, 8, stream);
  nce_row_kernel<<<NROWS, NTHR, 0, stream>>>(noise, actual, target, acc, ticket, out);
}